// Round 6
// baseline (1097.522 us; speedup 1.0000x reference)
//
#include <hip/hip_runtime.h>
#include <hip/hip_bf16.h>

#define NNODES 20000
#define NEDGES 640000
#define DIM 256
#define ND (NNODES * DIM)
#define BN_EPS 1e-5f

typedef __bf16 bf16_t;
typedef __attribute__((ext_vector_type(8))) __bf16 bf16x8;
typedef __attribute__((ext_vector_type(4))) __bf16 bf16x4;
typedef __attribute__((ext_vector_type(4))) float f32x4;

// ---------------------------------------------------------------- utilities
__global__ void zero_i(int* __restrict__ p, int n) {
    int i = blockIdx.x * blockDim.x + threadIdx.x;
    if (i < n) p[i] = 0;
}
__global__ void zero_f(float* __restrict__ p, int n) {
    int i = blockIdx.x * blockDim.x + threadIdx.x;
    if (i < n) p[i] = 0.f;
}

// ---------------------------------------------------------------- CSR build
__global__ void hist_k(const int* __restrict__ dst, int* __restrict__ deg) {
    int e = blockIdx.x * blockDim.x + threadIdx.x;
    if (e < NEDGES) atomicAdd(&deg[dst[e]], 1);
}

__global__ void scan_k(const int* __restrict__ deg, int* __restrict__ off,
                       int* __restrict__ cursor) {
    __shared__ int sm[1024];
    __shared__ int carry_s;
    const int t = threadIdx.x;
    if (t == 0) carry_s = 0;
    __syncthreads();
    for (int base = 0; base < NNODES; base += 1024) {
        int i = base + t;
        int val = (i < NNODES) ? deg[i] : 0;
        sm[t] = val;
        __syncthreads();
        for (int ofs = 1; ofs < 1024; ofs <<= 1) {
            int add = (t >= ofs) ? sm[t - ofs] : 0;
            __syncthreads();
            sm[t] += add;
            __syncthreads();
        }
        int inc = sm[t];
        int carry = carry_s;
        int exc = carry + inc - val;
        if (i < NNODES) { off[i] = exc; cursor[i] = exc; }
        __syncthreads();
        if (t == 1023) carry_s = carry + sm[1023];
        __syncthreads();
    }
    if (t == 0) off[NNODES] = carry_s;
}

__global__ void scatter_k(const int* __restrict__ src, const int* __restrict__ dst,
                          int* __restrict__ cursor, int* __restrict__ ssrc) {
    int e = blockIdx.x * blockDim.x + threadIdx.x;
    if (e < NEDGES) {
        int d = dst[e];
        int pos = atomicAdd(&cursor[d], 1);
        ssrc[pos] = src[e];
    }
}

// ---------------------------------------------------------------- fp32 -> bf16 hi/lo split
__global__ void convx_k(const float* __restrict__ x, bf16_t* __restrict__ xhi,
                        bf16_t* __restrict__ xlo) {
    int i = blockIdx.x * blockDim.x + threadIdx.x;
    if (i >= ND / 4) return;
    float4 f = ((const float4*)x)[i];
    float ff[4] = {f.x, f.y, f.z, f.w};
    bf16x4 hv, lv;
    #pragma unroll
    for (int j = 0; j < 4; ++j) {
        bf16_t h = (bf16_t)ff[j];
        hv[j] = h;
        lv[j] = (bf16_t)(ff[j] - (float)h);
    }
    *(bf16x4*)(xhi + (size_t)i * 4) = hv;
    *(bf16x4*)(xlo + (size_t)i * 4) = lv;
}

// ---------------------------------------------------------------- W transpose + split
__global__ void convw_k(const float* __restrict__ Wq, const float* __restrict__ Wk,
                        const float* __restrict__ Wv, const float* __restrict__ Ws,
                        bf16_t* __restrict__ wthi, bf16_t* __restrict__ wtlo) {
    __shared__ float sm[32][257];
    const int matIdx = blockIdx.y;          // l*4 + mat
    const int l = matIdx >> 2, mat = matIdx & 3;
    const int k0 = blockIdx.x * 32;
    const int t = threadIdx.x;              // col
    const float* W = ((mat == 0) ? Wq : (mat == 1) ? Wk : (mat == 2) ? Wv : Ws)
                     + (size_t)l * 65536;
    for (int rr = 0; rr < 32; ++rr)
        sm[rr][t] = W[(size_t)(k0 + rr) * 256 + t];
    __syncthreads();
    size_t off = (size_t)matIdx * 65536 + (size_t)t * 256 + k0;
    #pragma unroll
    for (int c = 0; c < 4; ++c) {
        bf16x8 hv, lv;
        #pragma unroll
        for (int j = 0; j < 8; ++j) {
            float f = sm[c * 8 + j][t];
            bf16_t h = (bf16_t)f;
            hv[j] = h;
            lv[j] = (bf16_t)(f - (float)h);
        }
        *(bf16x8*)(wthi + off + c * 8) = hv;
        *(bf16x8*)(wtlo + off + c * 8) = lv;
    }
}

// ---------------------------------------------------------------- MFMA QKVS GEMM
// qkvs[N][1024] = X @ [Wq|Wk|Wv|Ws] + bias, split-bf16 3-term.
// 2-stage register pipeline, barrier-free/LDS-free. grid (157, 8), 256 thr.
#define GLOAD(P, K0) do {                                                      \
    const int koff_ = (K0) + l4 * 8;                                           \
    _Pragma("unroll") for (int f = 0; f < 4; ++f) {                            \
        int row_ = rowb + f * 16;                                              \
        bool okr_ = row_ < NNODES;                                             \
        P##ah[f] = okr_ ? *(const bf16x8*)(Xhi + (size_t)row_ * 256 + koff_) : zv; \
        P##al[f] = okr_ ? *(const bf16x8*)(Xlo + (size_t)row_ * 256 + koff_) : zv; \
        int col_ = colb + f * 16;                                              \
        P##bh[f] = *(const bf16x8*)(Whi + (size_t)col_ * 256 + koff_);         \
        P##bl[f] = *(const bf16x8*)(Wlo + (size_t)col_ * 256 + koff_);         \
    } } while (0)

#define GMFMA(P) do {                                                          \
    _Pragma("unroll") for (int i = 0; i < 4; ++i)                              \
    _Pragma("unroll") for (int j = 0; j < 4; ++j) {                            \
        acc[i][j] = __builtin_amdgcn_mfma_f32_16x16x32_bf16(P##ah[i], P##bh[j], acc[i][j], 0, 0, 0); \
        acc[i][j] = __builtin_amdgcn_mfma_f32_16x16x32_bf16(P##ah[i], P##bl[j], acc[i][j], 0, 0, 0); \
        acc[i][j] = __builtin_amdgcn_mfma_f32_16x16x32_bf16(P##al[i], P##bh[j], acc[i][j], 0, 0, 0); \
    } } while (0)

__launch_bounds__(256, 2)
__global__ void gemm_mfma(const bf16_t* __restrict__ Xhi, const bf16_t* __restrict__ Xlo,
                          const bf16_t* __restrict__ Wthi, const bf16_t* __restrict__ Wtlo,
                          const float* __restrict__ bq, const float* __restrict__ bk,
                          const float* __restrict__ bv, const float* __restrict__ bs,
                          float* __restrict__ qkvs) {
    const int mat = blockIdx.y >> 1;          // 0..3 (block spans one mat)
    const int cm0 = (blockIdx.y & 1) * 128;   // col-in-mat base
    const int m0  = blockIdx.x * 128;

    const bf16_t* Whi = Wthi + (size_t)mat * 65536;
    const bf16_t* Wlo = Wtlo + (size_t)mat * 65536;
    const float* bias = (mat == 0) ? bq : (mat == 1) ? bk : (mat == 2) ? bv : bs;

    const int wid  = threadIdx.x >> 6;
    const int wr   = wid >> 1, wc = wid & 1;
    const int lane = threadIdx.x & 63;
    const int l15  = lane & 15, l4 = lane >> 4;

    const int rowb = m0 + wr * 64 + l15;
    const int colb = cm0 + wc * 64 + l15;     // in-mat col of B fragments

    f32x4 acc[4][4];
    #pragma unroll
    for (int i = 0; i < 4; ++i)
        #pragma unroll
        for (int j = 0; j < 4; ++j) acc[i][j] = (f32x4){0.f, 0.f, 0.f, 0.f};

    const bf16x8 zv = {};
    bf16x8 Aah[4], Aal[4], Abh[4], Abl[4];
    bf16x8 Bah[4], Bal[4], Bbh[4], Bbl[4];

    GLOAD(A, 0);
    #pragma unroll
    for (int k0 = 0; k0 < 256; k0 += 64) {
        GLOAD(B, k0 + 32);          // prefetch next step while A computes
        GMFMA(A);
        if (k0 + 64 < 256) GLOAD(A, k0 + 64);
        GMFMA(B);
    }

    #pragma unroll
    for (int j = 0; j < 4; ++j) {
        int colm = colb + j * 16;
        float b = bias[colm];
        int gcol = mat * 256 + colm;
        #pragma unroll
        for (int i = 0; i < 4; ++i) {
            int rbase = m0 + wr * 64 + i * 16 + l4 * 4;
            #pragma unroll
            for (int r = 0; r < 4; ++r) {
                int row = rbase + r;
                if (row < NNODES)
                    qkvs[(size_t)row * 1024 + gcol] = acc[i][j][r] + b;
            }
        }
    }
}

// ---------------------------------------------------------------- attention
// block = dst node; wave h = head h; 8 groups of 8 lanes, private online
// softmax per group with defer-max (T13); depth-2 k/v pipeline (2 named slots).
// qkvs row: q @ +0, k @ +256, v @ +512, s @ +768 (stride 1024).
#define ALOAD(K0, K1, V0, V1, SN) do {                                         \
    const float* r_ = qkvs + (size_t)(SN) * 1024;                              \
    K0 = *(const float4*)(r_ + 256 + hoff);                                    \
    K1 = *(const float4*)(r_ + 256 + hoff + 4);                                \
    V0 = *(const float4*)(r_ + 512 + hoff);                                    \
    V1 = *(const float4*)(r_ + 512 + hoff + 4);                                \
} while (0)

#define ACOMP(KD0, KD1, VD0, VD1, VLD) do {                                    \
    float dot_ = q0.x*KD0.x + q0.y*KD0.y + q0.z*KD0.z + q0.w*KD0.w             \
               + q1.x*KD1.x + q1.y*KD1.y + q1.z*KD1.z + q1.w*KD1.w;            \
    dot_ += __shfl_xor(dot_, 1, 64);                                           \
    dot_ += __shfl_xor(dot_, 2, 64);                                           \
    dot_ += __shfl_xor(dot_, 4, 64);                                           \
    float score_ = (VLD) ? dot_ * 0.125f : -3.0e38f;                           \
    if (__any(score_ > m + 8.f)) {                                             \
        float nm_ = fmaxf(m, score_);                                          \
        float sc_ = __expf(m - nm_);                                           \
        l *= sc_;                                                              \
        a0.x *= sc_; a0.y *= sc_; a0.z *= sc_; a0.w *= sc_;                    \
        a1.x *= sc_; a1.y *= sc_; a1.z *= sc_; a1.w *= sc_;                    \
        m = nm_;                                                               \
    }                                                                          \
    float e_ = (VLD) ? __expf(score_ - m) : 0.f;                               \
    l += e_;                                                                   \
    a0.x += e_*VD0.x; a0.y += e_*VD0.y; a0.z += e_*VD0.z; a0.w += e_*VD0.w;    \
    a1.x += e_*VD1.x; a1.y += e_*VD1.y; a1.z += e_*VD1.z; a1.w += e_*VD1.w;    \
} while (0)

__launch_bounds__(256, 4)
__global__ void attn_k(const float* __restrict__ qkvs, const int* __restrict__ off,
                       const int* __restrict__ ssrc, float* __restrict__ out) {
    const int node = blockIdx.x;
    const int h    = threadIdx.x >> 6;
    const int lane = threadIdx.x & 63;
    const int g    = lane >> 3;
    const int d8   = lane & 7;
    const int hoff = h * 64 + d8 * 8;

    const float* nrow = qkvs + (size_t)node * 1024;
    const float4 q0 = *(const float4*)(nrow + hoff);
    const float4 q1 = *(const float4*)(nrow + hoff + 4);
    const int p0 = off[node], p1 = off[node + 1];
    const int nmax = (p1 - p0 + 7) >> 3;

    float m = -3.0e38f, l = 0.f;
    float4 a0 = make_float4(0.f, 0.f, 0.f, 0.f), a1 = a0;
    float4 kA0 = a0, kA1 = a0, vA0 = a0, vA1 = a0;
    float4 kB0 = a0, kB1 = a0, vB0 = a0, vB1 = a0;

    int pA = p0 + g, pB = pA + 8;
    bool vldA = pA < p1, vldB = pB < p1;
    if (vldA) { int sn = ssrc[pA]; ALOAD(kA0, kA1, vA0, vA1, sn); }
    if (vldB) { int sn = ssrc[pB]; ALOAD(kB0, kB1, vB0, vB1, sn); }
    int pn = pA + 16;

    for (int t = 0; t < nmax; t += 2) {
        bool vN = pn < p1;
        int sn = vN ? ssrc[pn] : 0;              // issue early; latency hides under ACOMP
        ACOMP(kA0, kA1, vA0, vA1, vldA);
        if (vN) ALOAD(kA0, kA1, vA0, vA1, sn);   // prefetch t+2 into slot A
        vldA = vN; pn += 8;

        vN = pn < p1;
        sn = vN ? ssrc[pn] : 0;
        ACOMP(kB0, kB1, vB0, vB1, vldB);
        if (vN) ALOAD(kB0, kB1, vB0, vB1, sn);   // prefetch t+3 into slot B
        vldB = vN; pn += 8;
    }

    // merge the 8 groups
    float M = m;
    M = fmaxf(M, __shfl_xor(M, 8, 64));
    M = fmaxf(M, __shfl_xor(M, 16, 64));
    M = fmaxf(M, __shfl_xor(M, 32, 64));
    float r = (m > -1.0e37f) ? __expf(m - M) : 0.f;
    float lr = l * r;
    lr += __shfl_xor(lr, 8, 64);
    lr += __shfl_xor(lr, 16, 64);
    lr += __shfl_xor(lr, 32, 64);
    a0.x *= r; a0.y *= r; a0.z *= r; a0.w *= r;
    a1.x *= r; a1.y *= r; a1.z *= r; a1.w *= r;
    #pragma unroll
    for (int o = 8; o <= 32; o <<= 1) {
        a0.x += __shfl_xor(a0.x, o, 64); a0.y += __shfl_xor(a0.y, o, 64);
        a0.z += __shfl_xor(a0.z, o, 64); a0.w += __shfl_xor(a0.w, o, 64);
        a1.x += __shfl_xor(a1.x, o, 64); a1.y += __shfl_xor(a1.y, o, 64);
        a1.w += __shfl_xor(a1.w, o, 64); a1.z += __shfl_xor(a1.z, o, 64);
    }

    if (g == 0) {
        float inv = (lr > 0.f) ? 1.f / lr : 0.f;
        float4 s0 = *(const float4*)(nrow + 768 + hoff);
        float4 s1 = *(const float4*)(nrow + 768 + hoff + 4);
        float4 o0 = make_float4(a0.x * inv + s0.x, a0.y * inv + s0.y,
                                a0.z * inv + s0.z, a0.w * inv + s0.w);
        float4 o1 = make_float4(a1.x * inv + s1.x, a1.y * inv + s1.y,
                                a1.z * inv + s1.z, a1.w * inv + s1.w);
        *(float4*)(out + (size_t)node * 256 + hoff)     = o0;
        *(float4*)(out + (size_t)node * 256 + hoff + 4) = o1;
    }
}

// ---------------------------------------------------------------- batchnorm
__global__ void bn_stats(const float* __restrict__ y, float* __restrict__ colsum,
                         float* __restrict__ colsq) {
    int col = threadIdx.x;
    float sum = 0.f, sq = 0.f;
    for (int r = blockIdx.x; r < NNODES; r += gridDim.x) {
        float val = y[(size_t)r * 256 + col];
        sum += val;
        sq  += val * val;
    }
    atomicAdd(&colsum[col], sum);
    atomicAdd(&colsq[col], sq);
}

__global__ void bn_apply(const float* __restrict__ y, const float* __restrict__ colsum,
                         const float* __restrict__ colsq, const float* __restrict__ gamma,
                         const float* __restrict__ beta, bf16_t* __restrict__ xhi,
                         bf16_t* __restrict__ xlo) {
    int i4 = blockIdx.x * blockDim.x + threadIdx.x;
    if (i4 >= ND / 4) return;
    const float invN = 1.0f / NNODES;
    float4 yv = ((const float4*)y)[i4];
    int c0 = (i4 & 63) * 4;
    float yy[4] = {yv.x, yv.y, yv.z, yv.w};
    bf16x4 hv, lv;
    #pragma unroll
    for (int j = 0; j < 4; ++j) {
        int c = c0 + j;
        float mean = colsum[c] * invN;
        float var  = colsq[c] * invN - mean * mean;
        float scl  = gamma[c] * rsqrtf(var + BN_EPS);
        float val  = fmaxf((yy[j] - mean) * scl + beta[c], 0.f);
        bf16_t h = (bf16_t)val;
        hv[j] = h;
        lv[j] = (bf16_t)(val - (float)h);
    }
    *(bf16x4*)(xhi + (size_t)i4 * 4) = hv;
    *(bf16x4*)(xlo + (size_t)i4 * 4) = lv;
}

// ---------------------------------------------------------------- launch
extern "C" void kernel_launch(void* const* d_in, const int* in_sizes, int n_in,
                              void* d_out, int out_size, void* d_ws, size_t ws_size,
                              hipStream_t stream) {
    const float* x    = (const float*)d_in[0];
    const int*   ei   = (const int*)d_in[1];
    const float* Wq   = (const float*)d_in[2];
    const float* bq   = (const float*)d_in[3];
    const float* Wk   = (const float*)d_in[4];
    const float* bk   = (const float*)d_in[5];
    const float* Wv   = (const float*)d_in[6];
    const float* bv   = (const float*)d_in[7];
    const float* Ws   = (const float*)d_in[8];
    const float* bs   = (const float*)d_in[9];
    const float* bn_g = (const float*)d_in[10];
    const float* bn_b = (const float*)d_in[11];
    float* out = (float*)d_out;

    float* ws    = (float*)d_ws;
    float* qkvs  = ws;                          // 4*ND f32 ([N][1024])
    float* ybuf  = ws + 4 * (size_t)ND;         // ND f32
    float* colstats = ws + 5 * (size_t)ND;      // 512 f32
    bf16_t* xhi  = (bf16_t*)(colstats + 512);   // ND bf16
    bf16_t* xlo  = xhi + (size_t)ND;            // ND bf16
    bf16_t* wthi = xlo + (size_t)ND;            // 12*65536 bf16
    bf16_t* wtlo = wthi + 12 * 65536;           // 12*65536 bf16
    int* ip     = (int*)(wtlo + 12 * 65536);
    int* deg    = ip;
    int* offs   = ip + NNODES;                  // NNODES+1
    int* cursor = ip + 2 * NNODES + 1;
    int* ssrc   = ip + 3 * NNODES + 1;          // NEDGES
    const int* esrc = ei;
    const int* edst = ei + NEDGES;

    zero_i<<<(NNODES + 255) / 256, 256, 0, stream>>>(deg, NNODES);
    hist_k<<<(NEDGES + 255) / 256, 256, 0, stream>>>(edst, deg);
    scan_k<<<1, 1024, 0, stream>>>(deg, offs, cursor);
    scatter_k<<<(NEDGES + 255) / 256, 256, 0, stream>>>(esrc, edst, cursor, ssrc);

    convx_k<<<(ND / 4 + 255) / 256, 256, 0, stream>>>(x, xhi, xlo);
    convw_k<<<dim3(8, 12), 256, 0, stream>>>(Wq, Wk, Wv, Ws, wthi, wtlo);

    for (int l = 0; l < 3; ++l) {
        dim3 gg((NNODES + 127) / 128, 8);
        gemm_mfma<<<gg, 256, 0, stream>>>(xhi, xlo,
            wthi + (size_t)l * 4 * 65536, wtlo + (size_t)l * 4 * 65536,
            bq + (size_t)l * 256, bk + (size_t)l * 256,
            bv + (size_t)l * 256, bs + (size_t)l * 256,
            qkvs);

        float* yout = (l == 2) ? out : ybuf;
        attn_k<<<NNODES, 256, 0, stream>>>(qkvs, offs, ssrc, yout);

        if (l < 2) {
            zero_f<<<2, 256, 0, stream>>>(colstats, 512);
            bn_stats<<<256, 256, 0, stream>>>(ybuf, colstats, colstats + 256);
            bn_apply<<<(ND / 4 + 255) / 256, 256, 0, stream>>>(
                ybuf, colstats, colstats + 256,
                bn_g + (size_t)l * 256, bn_b + (size_t)l * 256, xhi, xlo);
        }
    }
}

// Round 7
// 746.361 us; speedup vs baseline: 1.4705x; 1.4705x over previous
//
#include <hip/hip_runtime.h>
#include <hip/hip_bf16.h>

#define NNODES 20000
#define NEDGES 640000
#define DIM 256
#define ND (NNODES * DIM)
#define BN_EPS 1e-5f

typedef __bf16 bf16_t;
typedef __attribute__((ext_vector_type(8))) __bf16 bf16x8;
typedef __attribute__((ext_vector_type(4))) __bf16 bf16x4;
typedef __attribute__((ext_vector_type(4))) float f32x4;

// ---------------------------------------------------------------- utilities
__global__ void zero_i(int* __restrict__ p, int n) {
    int i = blockIdx.x * blockDim.x + threadIdx.x;
    if (i < n) p[i] = 0;
}
__global__ void zero_f(float* __restrict__ p, int n) {
    int i = blockIdx.x * blockDim.x + threadIdx.x;
    if (i < n) p[i] = 0.f;
}

// ---------------------------------------------------------------- CSR build
__global__ void hist_k(const int* __restrict__ dst, int* __restrict__ deg) {
    int e = blockIdx.x * blockDim.x + threadIdx.x;
    if (e < NEDGES) atomicAdd(&deg[dst[e]], 1);
}

// single block, 1024 threads, 20 elements per thread -> one block-scan pass
__global__ void scan_k(const int* __restrict__ deg, int* __restrict__ off,
                       int* __restrict__ cursor) {
    __shared__ int part[1024];
    const int t = threadIdx.x;
    const int base = t * 20;
    int loc[20];
    int sum = 0;
    #pragma unroll
    for (int i = 0; i < 20; ++i) {
        int idx = base + i;
        int v = (idx < NNODES) ? deg[idx] : 0;
        loc[i] = sum;            // exclusive prefix within this thread's chunk
        sum += v;
    }
    part[t] = sum;
    __syncthreads();
    for (int ofs = 1; ofs < 1024; ofs <<= 1) {
        int add = (t >= ofs) ? part[t - ofs] : 0;
        __syncthreads();
        part[t] += add;
        __syncthreads();
    }
    const int texc = part[t] - sum;  // exclusive prefix of this chunk
    #pragma unroll
    for (int i = 0; i < 20; ++i) {
        int idx = base + i;
        if (idx < NNODES) {
            int e = texc + loc[i];
            off[idx] = e;
            cursor[idx] = e;
        }
    }
    if (t == 1023) off[NNODES] = part[1023];
}

__global__ void scatter_k(const int* __restrict__ src, const int* __restrict__ dst,
                          int* __restrict__ cursor, int* __restrict__ ssrc) {
    int e = blockIdx.x * blockDim.x + threadIdx.x;
    if (e < NEDGES) {
        int d = dst[e];
        int pos = atomicAdd(&cursor[d], 1);
        ssrc[pos] = src[e];
    }
}

// ---------------------------------------------------------------- fp32 -> bf16 hi/lo split
__global__ void convx_k(const float* __restrict__ x, bf16_t* __restrict__ xhi,
                        bf16_t* __restrict__ xlo) {
    int i = blockIdx.x * blockDim.x + threadIdx.x;
    if (i >= ND / 4) return;
    float4 f = ((const float4*)x)[i];
    float ff[4] = {f.x, f.y, f.z, f.w};
    bf16x4 hv, lv;
    #pragma unroll
    for (int j = 0; j < 4; ++j) {
        bf16_t h = (bf16_t)ff[j];
        hv[j] = h;
        lv[j] = (bf16_t)(ff[j] - (float)h);
    }
    *(bf16x4*)(xhi + (size_t)i * 4) = hv;
    *(bf16x4*)(xlo + (size_t)i * 4) = lv;
}

// ---------------------------------------------------------------- W transpose + split
__global__ void convw_k(const float* __restrict__ Wq, const float* __restrict__ Wk,
                        const float* __restrict__ Wv, const float* __restrict__ Ws,
                        bf16_t* __restrict__ wthi, bf16_t* __restrict__ wtlo) {
    __shared__ float sm[32][257];
    const int matIdx = blockIdx.y;          // l*4 + mat
    const int l = matIdx >> 2, mat = matIdx & 3;
    const int k0 = blockIdx.x * 32;
    const int t = threadIdx.x;              // col
    const float* W = ((mat == 0) ? Wq : (mat == 1) ? Wk : (mat == 2) ? Wv : Ws)
                     + (size_t)l * 65536;
    for (int rr = 0; rr < 32; ++rr)
        sm[rr][t] = W[(size_t)(k0 + rr) * 256 + t];
    __syncthreads();
    size_t off = (size_t)matIdx * 65536 + (size_t)t * 256 + k0;
    #pragma unroll
    for (int c = 0; c < 4; ++c) {
        bf16x8 hv, lv;
        #pragma unroll
        for (int j = 0; j < 8; ++j) {
            float f = sm[c * 8 + j][t];
            bf16_t h = (bf16_t)f;
            hv[j] = h;
            lv[j] = (bf16_t)(f - (float)h);
        }
        *(bf16x8*)(wthi + off + c * 8) = hv;
        *(bf16x8*)(wtlo + off + c * 8) = lv;
    }
}

// ---------------------------------------------------------------- MFMA QKVS GEMM
// LDS-staged A (hi/lo), double-buffered via global_load_lds(16B); B direct from
// L2-hot Wt. 128x128 tile, BK=32, 4 waves of 64x64. Outputs: q,s fp32 into
// qs[N][512]; k,v bf16 into kv[N][512].
#define STAGE(B, K0) do {                                                       \
    __builtin_amdgcn_global_load_lds(                                           \
        (const __attribute__((address_space(1))) void*)(Xhi + (size_t)gr0 * 256 + (K0) + sseg0 * 8), \
        (__attribute__((address_space(3))) void*)(&AhS[B][sflat0 * 8]), 16, 0, 0); \
    __builtin_amdgcn_global_load_lds(                                           \
        (const __attribute__((address_space(1))) void*)(Xhi + (size_t)gr1 * 256 + (K0) + sseg1 * 8), \
        (__attribute__((address_space(3))) void*)(&AhS[B][sflat1 * 8]), 16, 0, 0); \
    __builtin_amdgcn_global_load_lds(                                           \
        (const __attribute__((address_space(1))) void*)(Xlo + (size_t)gr0 * 256 + (K0) + sseg0 * 8), \
        (__attribute__((address_space(3))) void*)(&AlS[B][sflat0 * 8]), 16, 0, 0); \
    __builtin_amdgcn_global_load_lds(                                           \
        (const __attribute__((address_space(1))) void*)(Xlo + (size_t)gr1 * 256 + (K0) + sseg1 * 8), \
        (__attribute__((address_space(3))) void*)(&AlS[B][sflat1 * 8]), 16, 0, 0); \
} while (0)

__launch_bounds__(256, 2)
__global__ void gemm_mfma(const bf16_t* __restrict__ Xhi, const bf16_t* __restrict__ Xlo,
                          const bf16_t* __restrict__ Wthi, const bf16_t* __restrict__ Wtlo,
                          const float* __restrict__ bq, const float* __restrict__ bk,
                          const float* __restrict__ bv, const float* __restrict__ bs,
                          float* __restrict__ qs, bf16_t* __restrict__ kv) {
    __shared__ bf16_t AhS[2][128 * 32];   // 8 KB per buffer
    __shared__ bf16_t AlS[2][128 * 32];

    const int mat = blockIdx.y >> 1;          // 0=q 1=k 2=v 3=s
    const int cm0 = (blockIdx.y & 1) * 128;   // col-in-mat base
    const int m0  = blockIdx.x * 128;

    const bf16_t* Whi = Wthi + (size_t)mat * 65536;
    const bf16_t* Wlo = Wtlo + (size_t)mat * 65536;
    const float* bias = (mat == 0) ? bq : (mat == 1) ? bk : (mat == 2) ? bv : bs;

    const int tid  = threadIdx.x;
    const int wid  = tid >> 6;
    const int wr   = wid >> 1, wc = wid & 1;
    const int lane = tid & 63;
    const int l15  = lane & 15, l4 = lane >> 4;

    const int colb = cm0 + wc * 64 + l15;     // in-mat col of B fragments

    // staging slots: flat = tid (+256); row = flat>>2, 16B-segment = flat&3
    const int sflat0 = tid, sflat1 = tid + 256;
    const int srow0 = sflat0 >> 2, sseg0 = sflat0 & 3;
    const int srow1 = sflat1 >> 2, sseg1 = sflat1 & 3;
    const int gr0 = (m0 + srow0 < NNODES) ? m0 + srow0 : NNODES - 1;  // clamp (masked at store)
    const int gr1 = (m0 + srow1 < NNODES) ? m0 + srow1 : NNODES - 1;

    f32x4 acc[4][4];
    #pragma unroll
    for (int i = 0; i < 4; ++i)
        #pragma unroll
        for (int j = 0; j < 4; ++j) acc[i][j] = (f32x4){0.f, 0.f, 0.f, 0.f};

    STAGE(0, 0);
    __syncthreads();   // drains vmcnt: buf0 ready

    for (int t = 0; t < 8; ++t) {
        const int cur = t & 1;
        if (t < 7) STAGE(cur ^ 1, (t + 1) * 32);

        bf16x8 ah[4], al[4], bh[4], bl[4];
        #pragma unroll
        for (int f = 0; f < 4; ++f) {
            const int arow = wr * 64 + f * 16 + l15;
            ah[f] = *(const bf16x8*)&AhS[cur][arow * 32 + l4 * 8];
            al[f] = *(const bf16x8*)&AlS[cur][arow * 32 + l4 * 8];
            const bf16_t* wp = Whi + (size_t)(colb + f * 16) * 256 + t * 32 + l4 * 8;
            const bf16_t* wl = Wlo + (size_t)(colb + f * 16) * 256 + t * 32 + l4 * 8;
            bh[f] = *(const bf16x8*)wp;
            bl[f] = *(const bf16x8*)wl;
        }
        #pragma unroll
        for (int i = 0; i < 4; ++i)
            #pragma unroll
            for (int j = 0; j < 4; ++j) {
                acc[i][j] = __builtin_amdgcn_mfma_f32_16x16x32_bf16(ah[i], bh[j], acc[i][j], 0, 0, 0);
                acc[i][j] = __builtin_amdgcn_mfma_f32_16x16x32_bf16(ah[i], bl[j], acc[i][j], 0, 0, 0);
                acc[i][j] = __builtin_amdgcn_mfma_f32_16x16x32_bf16(al[i], bh[j], acc[i][j], 0, 0, 0);
            }
        __syncthreads();   // staging for next buf complete; reads of cur done
    }

    const bool isf32 = (mat == 0) || (mat == 3);
    const int obase = (mat == 0 || mat == 1) ? 0 : 256;
    #pragma unroll
    for (int j = 0; j < 4; ++j) {
        const int colm = colb + j * 16;        // 0..255 within mat
        const float b = bias[colm];
        #pragma unroll
        for (int i = 0; i < 4; ++i) {
            const int rbase = m0 + wr * 64 + i * 16 + l4 * 4;
            #pragma unroll
            for (int r = 0; r < 4; ++r) {
                const int row = rbase + r;
                if (row < NNODES) {
                    float val = acc[i][j][r] + b;
                    if (isf32) qs[(size_t)row * 512 + obase + colm] = val;
                    else       kv[(size_t)row * 512 + obase + colm] = (bf16_t)val;
                }
            }
        }
    }
}

// ---------------------------------------------------------------- attention
// block = dst node; wave h = head h; 8 groups of 8 lanes, private online
// softmax with defer-max; depth-2 k/v pipeline. kv row (bf16): k@0, v@256.
// qs row (fp32): q@0, s@256. Per edge per group: 2x16B bf16 loads (1KB/edge
// across the block -> half the fp32 gather traffic).
#define ALOAD(KD, VD, SN) do {                                                  \
    const bf16_t* r_ = kv + (size_t)(SN) * 512 + hoff;                          \
    KD = *(const bf16x8*)(r_);                                                  \
    VD = *(const bf16x8*)(r_ + 256);                                            \
} while (0)

#define ACOMP(KD, VD, VLD) do {                                                 \
    float dot_ = 0.f;                                                           \
    _Pragma("unroll") for (int j_ = 0; j_ < 8; ++j_) dot_ += qf[j_] * (float)KD[j_]; \
    dot_ += __shfl_xor(dot_, 1, 64);                                            \
    dot_ += __shfl_xor(dot_, 2, 64);                                            \
    dot_ += __shfl_xor(dot_, 4, 64);                                            \
    float score_ = (VLD) ? dot_ * 0.125f : -3.0e38f;                            \
    if (__any(score_ > m + 8.f)) {                                              \
        float nm_ = fmaxf(m, score_);                                           \
        float sc_ = __expf(m - nm_);                                            \
        l *= sc_;                                                               \
        _Pragma("unroll") for (int j_ = 0; j_ < 8; ++j_) a[j_] *= sc_;          \
        m = nm_;                                                                \
    }                                                                           \
    float e_ = (VLD) ? __expf(score_ - m) : 0.f;                                \
    l += e_;                                                                    \
    _Pragma("unroll") for (int j_ = 0; j_ < 8; ++j_) a[j_] += e_ * (float)VD[j_]; \
} while (0)

__launch_bounds__(256, 4)
__global__ void attn_k(const float* __restrict__ qs, const bf16_t* __restrict__ kv,
                       const int* __restrict__ off, const int* __restrict__ ssrc,
                       float* __restrict__ out) {
    const int node = blockIdx.x;
    const int h    = threadIdx.x >> 6;
    const int lane = threadIdx.x & 63;
    const int g    = lane >> 3;
    const int d8   = lane & 7;
    const int hoff = h * 64 + d8 * 8;

    const float* qrow = qs + (size_t)node * 512;
    const float4 q0 = *(const float4*)(qrow + hoff);
    const float4 q1 = *(const float4*)(qrow + hoff + 4);
    const float qf[8] = {q0.x, q0.y, q0.z, q0.w, q1.x, q1.y, q1.z, q1.w};
    const int p0 = off[node], p1 = off[node + 1];
    const int nmax = (p1 - p0 + 7) >> 3;

    float m = -3.0e38f, l = 0.f;
    float a[8] = {0.f, 0.f, 0.f, 0.f, 0.f, 0.f, 0.f, 0.f};
    bf16x8 kA = {}, vA = {}, kB = {}, vB = {};

    int pA = p0 + g, pB = pA + 8;
    bool vldA = pA < p1, vldB = pB < p1;
    if (vldA) { int sn = ssrc[pA]; ALOAD(kA, vA, sn); }
    if (vldB) { int sn = ssrc[pB]; ALOAD(kB, vB, sn); }
    int pn = pA + 16;

    for (int t = 0; t < nmax; t += 2) {
        bool vN = pn < p1;
        int sn = vN ? ssrc[pn] : 0;          // issue early; hides under ACOMP
        ACOMP(kA, vA, vldA);
        if (vN) ALOAD(kA, vA, sn);           // prefetch t+2 into slot A
        vldA = vN; pn += 8;

        vN = pn < p1;
        sn = vN ? ssrc[pn] : 0;
        ACOMP(kB, vB, vldB);
        if (vN) ALOAD(kB, vB, sn);           // prefetch t+3 into slot B
        vldB = vN; pn += 8;
    }

    // merge the 8 groups
    float M = m;
    M = fmaxf(M, __shfl_xor(M, 8, 64));
    M = fmaxf(M, __shfl_xor(M, 16, 64));
    M = fmaxf(M, __shfl_xor(M, 32, 64));
    float r = (m > -1.0e37f) ? __expf(m - M) : 0.f;
    float lr = l * r;
    lr += __shfl_xor(lr, 8, 64);
    lr += __shfl_xor(lr, 16, 64);
    lr += __shfl_xor(lr, 32, 64);
    #pragma unroll
    for (int j = 0; j < 8; ++j) {
        a[j] *= r;
        a[j] += __shfl_xor(a[j], 8, 64);
        a[j] += __shfl_xor(a[j], 16, 64);
        a[j] += __shfl_xor(a[j], 32, 64);
    }

    if (g == 0) {
        float inv = (lr > 0.f) ? 1.f / lr : 0.f;
        const float4 s0 = *(const float4*)(qrow + 256 + hoff);
        const float4 s1 = *(const float4*)(qrow + 256 + hoff + 4);
        float4 o0 = make_float4(a[0] * inv + s0.x, a[1] * inv + s0.y,
                                a[2] * inv + s0.z, a[3] * inv + s0.w);
        float4 o1 = make_float4(a[4] * inv + s1.x, a[5] * inv + s1.y,
                                a[6] * inv + s1.z, a[7] * inv + s1.w);
        *(float4*)(out + (size_t)node * 256 + hoff)     = o0;
        *(float4*)(out + (size_t)node * 256 + hoff + 4) = o1;
    }
}

// ---------------------------------------------------------------- batchnorm
__global__ void bn_stats(const float* __restrict__ y, float* __restrict__ colsum,
                         float* __restrict__ colsq) {
    int col = threadIdx.x;
    float sum = 0.f, sq = 0.f;
    for (int r = blockIdx.x; r < NNODES; r += gridDim.x) {
        float val = y[(size_t)r * 256 + col];
        sum += val;
        sq  += val * val;
    }
    atomicAdd(&colsum[col], sum);
    atomicAdd(&colsq[col], sq);
}

__global__ void bn_apply(const float* __restrict__ y, const float* __restrict__ colsum,
                         const float* __restrict__ colsq, const float* __restrict__ gamma,
                         const float* __restrict__ beta, bf16_t* __restrict__ xhi,
                         bf16_t* __restrict__ xlo) {
    int i4 = blockIdx.x * blockDim.x + threadIdx.x;
    if (i4 >= ND / 4) return;
    const float invN = 1.0f / NNODES;
    float4 yv = ((const float4*)y)[i4];
    int c0 = (i4 & 63) * 4;
    float yy[4] = {yv.x, yv.y, yv.z, yv.w};
    bf16x4 hv, lv;
    #pragma unroll
    for (int j = 0; j < 4; ++j) {
        int c = c0 + j;
        float mean = colsum[c] * invN;
        float var  = colsq[c] * invN - mean * mean;
        float scl  = gamma[c] * rsqrtf(var + BN_EPS);
        float val  = fmaxf((yy[j] - mean) * scl + beta[c], 0.f);
        bf16_t h = (bf16_t)val;
        hv[j] = h;
        lv[j] = (bf16_t)(val - (float)h);
    }
    *(bf16x4*)(xhi + (size_t)i4 * 4) = hv;
    *(bf16x4*)(xlo + (size_t)i4 * 4) = lv;
}

// ---------------------------------------------------------------- launch
extern "C" void kernel_launch(void* const* d_in, const int* in_sizes, int n_in,
                              void* d_out, int out_size, void* d_ws, size_t ws_size,
                              hipStream_t stream) {
    const float* x    = (const float*)d_in[0];
    const int*   ei   = (const int*)d_in[1];
    const float* Wq   = (const float*)d_in[2];
    const float* bq   = (const float*)d_in[3];
    const float* Wk   = (const float*)d_in[4];
    const float* bk   = (const float*)d_in[5];
    const float* Wv   = (const float*)d_in[6];
    const float* bv   = (const float*)d_in[7];
    const float* Ws   = (const float*)d_in[8];
    const float* bs   = (const float*)d_in[9];
    const float* bn_g = (const float*)d_in[10];
    const float* bn_b = (const float*)d_in[11];
    float* out = (float*)d_out;

    float* ws    = (float*)d_ws;
    float* qs    = ws;                          // 2*ND f32 ([N][512]: q|s)
    float* ybuf  = ws + 2 * (size_t)ND;         // ND f32
    float* colstats = ws + 3 * (size_t)ND;      // 512 f32
    bf16_t* kv   = (bf16_t*)(colstats + 512);   // 2*ND bf16 ([N][512]: k|v)
    bf16_t* xhi  = kv + 2 * (size_t)ND;         // ND bf16
    bf16_t* xlo  = xhi + (size_t)ND;            // ND bf16
    bf16_t* wthi = xlo + (size_t)ND;            // 12*65536 bf16
    bf16_t* wtlo = wthi + 12 * 65536;           // 12*65536 bf16
    int* ip     = (int*)(wtlo + 12 * 65536);
    int* deg    = ip;
    int* offs   = ip + NNODES;                  // NNODES+1
    int* cursor = ip + 2 * NNODES + 1;
    int* ssrc   = ip + 3 * NNODES + 1;          // NEDGES
    const int* esrc = ei;
    const int* edst = ei + NEDGES;

    zero_i<<<(NNODES + 255) / 256, 256, 0, stream>>>(deg, NNODES);
    hist_k<<<(NEDGES + 255) / 256, 256, 0, stream>>>(edst, deg);
    scan_k<<<1, 1024, 0, stream>>>(deg, offs, cursor);
    scatter_k<<<(NEDGES + 255) / 256, 256, 0, stream>>>(esrc, edst, cursor, ssrc);

    convx_k<<<(ND / 4 + 255) / 256, 256, 0, stream>>>(x, xhi, xlo);
    convw_k<<<dim3(8, 12), 256, 0, stream>>>(Wq, Wk, Wv, Ws, wthi, wtlo);

    for (int l = 0; l < 3; ++l) {
        dim3 gg((NNODES + 127) / 128, 8);
        gemm_mfma<<<gg, 256, 0, stream>>>(xhi, xlo,
            wthi + (size_t)l * 4 * 65536, wtlo + (size_t)l * 4 * 65536,
            bq + (size_t)l * 256, bk + (size_t)l * 256,
            bv + (size_t)l * 256, bs + (size_t)l * 256,
            qs, kv);

        float* yout = (l == 2) ? out : ybuf;
        attn_k<<<NNODES, 256, 0, stream>>>(qs, kv, offs, ssrc, yout);

        if (l < 2) {
            zero_f<<<2, 256, 0, stream>>>(colstats, 512);
            bn_stats<<<256, 256, 0, stream>>>(ybuf, colstats, colstats + 256);
            bn_apply<<<(ND / 4 + 255) / 256, 256, 0, stream>>>(
                ybuf, colstats, colstats + 256,
                bn_g + (size_t)l * 256, bn_b + (size_t)l * 256, xhi, xlo);
        }
    }
}